// Round 3
// baseline (768.018 us; speedup 1.0000x reference)
//
#include <hip/hip_runtime.h>
#include <hip/hip_bf16.h>
#include <cstdint>

#define SDIM 200
#define HDIM 128
#define IDIM 4
#define BDIM 1024
#define LDK 72      // bf16 staging leading dim per 64-wide K-half (144 B rows)
#define LDEF 132    // fp32 epilogue leading dim (528 B rows)

typedef __attribute__((ext_vector_type(8))) short short8;
typedef __attribute__((ext_vector_type(4))) float f32x4;

__device__ __forceinline__ ushort f32_to_bf16u(float f) {
    uint32_t u = __builtin_bit_cast(uint32_t, f);
    u += 0x7FFFu + ((u >> 16) & 1u);   // RNE
    return (ushort)(u >> 16);
}
__device__ __forceinline__ float bf16u_to_f32(ushort h) {
    uint32_t u = ((uint32_t)h) << 16;
    return __builtin_bit_cast(float, u);
}
__device__ __forceinline__ void split8(const float* p, uint4* hi, uint4* lo) {
    union { ushort u[8]; uint4 v; } xh, xl;
    #pragma unroll
    for (int j = 0; j < 8; ++j) {
        float f = p[j];
        ushort h = f32_to_bf16u(f);
        float r = f - bf16u_to_f32(h);
        xh.u[j] = h;
        xl.u[j] = f32_to_bf16u(r);
    }
    *hi = xh.v; *lo = xl.v;
}

// ---------------------------------------------------------------------------
// Kernel 1 (R6): ii-merged hat GEMM, HALF-K staging for occupancy.
// LDS = 36,864 B (one 64-wide K-half of W, hi+lo) -> 3-4 blocks/CU (was 2).
// A fragments rematerialized per (ii,st,kk) from L1/L2-hot item (compiler was
// already doing this at VGPR=128; we stop fighting it). Epilogue runs in two
// 64-row halves aliased over the W buffer (33,792 B <= 36,864 B).
// Grid = nbt x SDIM bt-major: XCD = s%8 (200 % 8 == 0), same-s blocks share
// the w panel in one XCD's L2.
// ---------------------------------------------------------------------------
__global__ __launch_bounds__(256, 3) void hat_gemm(const float* __restrict__ item,
                                                   const float* __restrict__ w,
                                                   float* __restrict__ hat,
                                                   int b0, int nbt) {
    __shared__ ushort lds[2 * 128 * LDK];     // 36,864 B: Wh | Wl (one K-half)
    ushort* Wh = lds;
    ushort* Wl = lds + 128 * LDK;
    float*  ef = (float*)lds;                 // 64 x LDEF fp32 = 33,792 B aliased

    const int blk = blockIdx.x;
    const int bt = blk / SDIM;                // bt-major ordering
    const int s  = blk % SDIM;
    const int t  = threadIdx.x;

    const int wave = t >> 6, lane = t & 63;
    const int wm = wave >> 1, wn = wave & 1;
    const int m0 = lane & 15, q = lane >> 4;

    // per-lane item base for A-fragment remat loads (row = wm*64 + tm*16 + m0)
    const float* ib = item +
        ((size_t)(b0 + bt * 128 + wm * 64 + m0) * SDIM + s) * HDIM;
    const float* wRow = w + (size_t)s * (IDIM * HDIM) * HDIM;

    #pragma unroll 1
    for (int ii = 0; ii < IDIM; ++ii) {
        const float* wB = wRow + (size_t)ii * HDIM * HDIM;

        f32x4 acc[4][4];
        #pragma unroll
        for (int tm = 0; tm < 4; ++tm)
            #pragma unroll
            for (int tn = 0; tn < 4; ++tn)
                acc[tm][tn] = (f32x4){0.f, 0.f, 0.f, 0.f};

        #pragma unroll
        for (int st = 0; st < 2; ++st) {
            __syncthreads();                  // prev readers of Wh/Wl|ef done

            // ---- stage one 64-wide K-half of W, split bf16 hi/lo ----
            #pragma unroll
            for (int c = t; c < 1024; c += 256) {
                int row = c >> 3, g = c & 7;
                uint4 hi, lo;
                split8(wB + (size_t)row * HDIM + st * 64 + g * 8, &hi, &lo);
                *(uint4*)(&Wh[row * LDK + g * 8]) = hi;
                *(uint4*)(&Wl[row * LDK + g * 8]) = lo;
            }
            __syncthreads();

            // ---- MFMA over this K-half; A remat per kk (32 VGPRs live) ----
            #pragma unroll
            for (int kk = 0; kk < 2; ++kk) {
                const int kof = kk * 32 + q * 8;      // q in [0,4) -> kof <= 56
                short8 a_h[4], a_l[4];
                #pragma unroll
                for (int tm = 0; tm < 4; ++tm) {
                    uint4 hi, lo;
                    split8(ib + (size_t)(tm * 16) * (SDIM * HDIM) + st * 64 + kof,
                           &hi, &lo);
                    a_h[tm] = __builtin_bit_cast(short8, hi);
                    a_l[tm] = __builtin_bit_cast(short8, lo);
                }
                short8 bh[4], bl[4];
                #pragma unroll
                for (int tn = 0; tn < 4; ++tn) {
                    int ro = (wn * 64 + tn * 16 + m0) * LDK + kof;
                    bh[tn] = *(const short8*)(&Wh[ro]);
                    bl[tn] = *(const short8*)(&Wl[ro]);
                }
                #pragma unroll
                for (int tm = 0; tm < 4; ++tm)
                    #pragma unroll
                    for (int tn = 0; tn < 4; ++tn) {
                        acc[tm][tn] = __builtin_amdgcn_mfma_f32_16x16x32_bf16(
                            a_h[tm], bl[tn], acc[tm][tn], 0, 0, 0);
                        acc[tm][tn] = __builtin_amdgcn_mfma_f32_16x16x32_bf16(
                            a_l[tm], bh[tn], acc[tm][tn], 0, 0, 0);
                        acc[tm][tn] = __builtin_amdgcn_mfma_f32_16x16x32_bf16(
                            a_h[tm], bh[tn], acc[tm][tn], 0, 0, 0);
                    }
            }
        }

        // ---- epilogue in two 64-row halves (ef aliases W buffer) ----
        #pragma unroll
        for (int eh = 0; eh < 2; ++eh) {
            __syncthreads();                  // MFMA reads (eh=0) / ef round (eh=1) done
            if (wm == eh) {
                #pragma unroll
                for (int tm = 0; tm < 4; ++tm) {
                    #pragma unroll
                    for (int tn = 0; tn < 4; ++tn) {
                        int col = wn * 64 + tn * 16 + m0;
                        #pragma unroll
                        for (int rg = 0; rg < 4; ++rg) {
                            int row = tm * 16 + q * 4 + rg;   // local row in [0,64)
                            ef[row * LDEF + col] = acc[tm][tn][rg];
                        }
                    }
                }
            }
            __syncthreads();
            #pragma unroll
            for (int c = t; c < 2048; c += 256) {            // 64 rows x 32 float4
                int row = c >> 5, cc = c & 31;
                int bl_ = bt * 128 + eh * 64 + row;
                float4 v = *(const float4*)(&ef[row * LDEF + cc * 4]);
                *(float4*)(hat + (((size_t)bl_ * IDIM + ii) * SDIM + s) * HDIM + cc * 4) = v;
            }
        }
    }
}

// ---------------------------------------------------------------------------
// Kernel 2 (R6): routing, 512 threads/block. Thread owns h-quad hq=(t&31)*4 and
// s-group sg=t>>5 (16 groups): rows s = sg + 16j, j<13 (j=12 only for sg<8).
// pf[13] = 52 VGPRs (was 100) -> no spill pressure, ~2x exposed parallelism.
// ---------------------------------------------------------------------------
__global__ __launch_bounds__(512) void routing4(const float* __restrict__ hat,
                                                const int* __restrict__ mask,
                                                float* __restrict__ out, int b0) {
    __shared__ float cw[SDIM];
    __shared__ float eall[SDIM];
    __shared__ float ew[SDIM];
    __shared__ float icp[16 * HDIM];
    __shared__ float ic[HDIM];
    __shared__ float icf[HDIM];
    __shared__ int   mk[SDIM];

    const int blk = blockIdx.x;
    const int bl = blk >> 2, ii = blk & 3;
    const int b = b0 + bl;
    const int t = threadIdx.x, lane = t & 63, wv = t >> 6;
    const int hq = (t & 31) * 4;
    const int sg = t >> 5;                    // [0,16), uniform per 32-lane group
    const bool has13 = (sg < 8);              // row sg+192 exists (< 200)
    const float* base = hat + ((size_t)bl * IDIM + ii) * (SDIM * HDIM);

    if (t < SDIM) mk[t] = mask[(size_t)b * SDIM + t];

    float4 pf[13];
    #pragma unroll
    for (int j = 0; j < 12; ++j)
        pf[j] = *(const float4*)(base + (size_t)(sg + 16 * j) * HDIM + hq);
    pf[12] = has13 ? *(const float4*)(base + (size_t)(sg + 192) * HDIM + hq)
                   : (float4){0.f, 0.f, 0.f, 0.f};
    __syncthreads();   // mk ready

    // ---- pass 0: uniform sw = 1/200, masked numerator
    {
        float4 u = {0.f, 0.f, 0.f, 0.f};
        #pragma unroll
        for (int j = 0; j < 12; ++j) {
            if (mk[sg + 16 * j]) {
                u.x += pf[j].x; u.y += pf[j].y; u.z += pf[j].z; u.w += pf[j].w;
            }
        }
        if (has13 && mk[sg + 192]) {
            u.x += pf[12].x; u.y += pf[12].y; u.z += pf[12].z; u.w += pf[12].w;
        }
        *(float4*)(&icp[sg * HDIM + hq]) = u;
    }
    __syncthreads();
    if (t < HDIM) {
        float v = 0.f;
        #pragma unroll
        for (int g = 0; g < 16; ++g) v += icp[g * HDIM + t];
        ic[t] = v * (1.0f / 200.0f);
    }
    __syncthreads();
    if (wv == 0) {
        float i0 = ic[lane], i1 = ic[lane + 64];
        float p = i0 * i0 + i1 * i1;
        #pragma unroll
        for (int off = 32; off > 0; off >>= 1) p += __shfl_xor(p, off);
        float fac = p / (1.0f + p) / sqrtf(p + 1e-9f);
        icf[lane] = i0 * fac;
        icf[lane + 64] = i1 * fac;
    }
    __syncthreads();

    for (int iter = 1; iter <= 2; ++iter) {
        // A: delta[s] = <hat_s, icf>; 13 independent 5-shuffle reductions
        float4 c4 = *(const float4*)(&icf[hq]);
        #pragma unroll
        for (int j = 0; j < 13; ++j) {
            float d = fmaf(pf[j].x, c4.x, fmaf(pf[j].y, c4.y,
                      fmaf(pf[j].z, c4.z, pf[j].w * c4.w)));
            d += __shfl_xor(d, 16);
            d += __shfl_xor(d, 8);
            d += __shfl_xor(d, 4);
            d += __shfl_xor(d, 2);
            d += __shfl_xor(d, 1);
            if ((t & 31) == 0 && (j < 12 || has13)) {
                int s = sg + 16 * j;
                cw[s] = (iter == 1) ? d : cw[s] + d;
            }
        }
        __syncthreads();

        // B1: block max (redundant per wave), exp
        float m = fmaxf(cw[lane], fmaxf(cw[lane + 64], cw[lane + 128]));
        if (lane < SDIM - 192) m = fmaxf(m, cw[lane + 192]);
        #pragma unroll
        for (int off = 32; off > 0; off >>= 1) m = fmaxf(m, __shfl_xor(m, off));
        if (t < SDIM) {
            float e = __expf(cw[t] - m);
            eall[t] = e;
            ew[t] = mk[t] ? e : 0.0f;
        }
        __syncthreads();

        // B2: denominator (redundant per wave; includes masked entries)
        float D = eall[lane] + eall[lane + 64] + eall[lane + 128]
                + ((lane < SDIM - 192) ? eall[lane + 192] : 0.0f);
        #pragma unroll
        for (int off = 32; off > 0; off >>= 1) D += __shfl_xor(D, off);

        // C: numerator u[h] = sum_s ew[s]*hat[s,h] from registers
        {
            float4 u = {0.f, 0.f, 0.f, 0.f};
            #pragma unroll
            for (int j = 0; j < 12; ++j) {
                float wgt = ew[sg + 16 * j];
                u.x = fmaf(wgt, pf[j].x, u.x);
                u.y = fmaf(wgt, pf[j].y, u.y);
                u.z = fmaf(wgt, pf[j].z, u.z);
                u.w = fmaf(wgt, pf[j].w, u.w);
            }
            float wgt = has13 ? ew[sg + 192] : 0.0f;
            u.x = fmaf(wgt, pf[12].x, u.x);
            u.y = fmaf(wgt, pf[12].y, u.y);
            u.z = fmaf(wgt, pf[12].z, u.z);
            u.w = fmaf(wgt, pf[12].w, u.w);
            *(float4*)(&icp[sg * HDIM + hq]) = u;
        }
        __syncthreads();

        // D: merge 16 s-group partials, divide by denominator
        if (t < HDIM) {
            float v = 0.f;
            #pragma unroll
            for (int g = 0; g < 16; ++g) v += icp[g * HDIM + t];
            ic[t] = v / D;
        }
        __syncthreads();

        // E: squash; iter1 -> icf, iter2 -> output
        if (wv == 0) {
            float i0 = ic[lane], i1 = ic[lane + 64];
            float p = i0 * i0 + i1 * i1;
            #pragma unroll
            for (int off = 32; off > 0; off >>= 1) p += __shfl_xor(p, off);
            float fac = p / (1.0f + p) / sqrtf(p + 1e-9f);
            if (iter == 1) {
                icf[lane] = i0 * fac;
                icf[lane + 64] = i1 * fac;
            } else {
                out[((size_t)b * IDIM + ii) * HDIM + lane]      = i0 * fac;
                out[((size_t)b * IDIM + ii) * HDIM + lane + 64] = i1 * fac;
            }
        }
        if (iter == 1) __syncthreads();
    }
}

extern "C" void kernel_launch(void* const* d_in, const int* in_sizes, int n_in,
                              void* d_out, int out_size, void* d_ws, size_t ws_size,
                              hipStream_t stream) {
    const float* item = nullptr;
    const int*   msk  = nullptr;
    const float* w    = nullptr;
    for (int i = 0; i < n_in; ++i) {
        if (in_sizes[i] == BDIM * SDIM * HDIM)             item = (const float*)d_in[i];
        else if (in_sizes[i] == BDIM * SDIM)               msk  = (const int*)d_in[i];
        else if (in_sizes[i] == SDIM * IDIM * HDIM * HDIM) w    = (const float*)d_in[i];
    }
    if (!item) item = (const float*)d_in[0];
    if (!msk)  msk  = (const int*)d_in[1];
    if (!w)    w    = (const float*)d_in[2];

    float* hat = (float*)d_ws;                 // (chunk,I,S,H) fp32 workspace
    float* out = (float*)d_out;

    const size_t perB = (size_t)IDIM * SDIM * HDIM * sizeof(float);
    size_t hatCap = ws_size / perB;
    int chunk = 512;
    if (hatCap < (size_t)chunk) chunk = (int)((hatCap / 128) * 128);
    if (chunk < 128) chunk = 128;
    for (int bb = 0; bb < BDIM; bb += chunk) {
        int cb = (BDIM - bb < chunk) ? (BDIM - bb) : chunk;
        int nbt = cb / 128;
        hat_gemm<<<nbt * SDIM, 256, 0, stream>>>(item, w, hat, bb, nbt);
        routing4<<<cb * IDIM, 512, 0, stream>>>(hat, msk, out, bb);
    }
}

// Round 4
// 615.172 us; speedup vs baseline: 1.2485x; 1.2485x over previous
//
#include <hip/hip_runtime.h>
#include <hip/hip_bf16.h>
#include <cstdint>

#define SDIM 200
#define HDIM 128
#define IDIM 4
#define BDIM 1024
#define LDK 72      // bf16 staging leading dim per 64-wide K-half (144 B rows)
#define LDEF 132    // fp32 epilogue leading dim (528 B rows)

typedef __attribute__((ext_vector_type(8))) short short8;
typedef __attribute__((ext_vector_type(4))) float f32x4;

__device__ __forceinline__ ushort f32_to_bf16u(float f) {
    uint32_t u = __builtin_bit_cast(uint32_t, f);
    u += 0x7FFFu + ((u >> 16) & 1u);   // RNE
    return (ushort)(u >> 16);
}
__device__ __forceinline__ float bf16u_to_f32(ushort h) {
    uint32_t u = ((uint32_t)h) << 16;
    return __builtin_bit_cast(float, u);
}
__device__ __forceinline__ void split8(const float* p, uint4* hi, uint4* lo) {
    union { ushort u[8]; uint4 v; } xh, xl;
    #pragma unroll
    for (int j = 0; j < 8; ++j) {
        float f = p[j];
        ushort h = f32_to_bf16u(f);
        float r = f - bf16u_to_f32(h);
        xh.u[j] = h;
        xl.u[j] = f32_to_bf16u(r);
    }
    *hi = xh.v; *lo = xl.v;
}

// ---------------------------------------------------------------------------
// Kernel 0 (R7): one-time W split prepass. w fp32 -> w_hi/w_lo bf16 (RNE + resid).
// Removes 16x-redundant split8 VALU from the hot GEMM.
// ---------------------------------------------------------------------------
__global__ __launch_bounds__(256) void wsplit(const float* __restrict__ w,
                                              ushort* __restrict__ whi,
                                              ushort* __restrict__ wlo) {
    const size_t N = (size_t)SDIM * IDIM * HDIM * HDIM / 8;   // 8-elem groups
    for (size_t g = (size_t)blockIdx.x * 256 + threadIdx.x; g < N;
         g += (size_t)gridDim.x * 256) {
        uint4 hi, lo;
        split8(w + g * 8, &hi, &lo);
        *(uint4*)(whi + g * 8) = hi;
        *(uint4*)(wlo + g * 8) = lo;
    }
}

// ---------------------------------------------------------------------------
// Kernel 1 (R7): ii-merged hat GEMM, M=64 tile, A fully register-resident.
// Grid = SDIM x (2*nbt), s-major (blk = s*nbt2 + btm). Per block:
//   - A (64 rows x K=128, split bf16 hi/lo) loaded+split ONCE -> 64 VGPRs,
//     resident across the whole ii loop. FETCH(item) = 1x by construction.
//   - W staged per (ii, K-half) as a pure 16-B copy from prepass arrays
//     (no split VALU). LDS = 36,864 B -> 3 blocks/CU (launch_bounds 256,3).
//   - Epilogue: 64 x LDEF fp32 transpose aliased over W buffers.
// ---------------------------------------------------------------------------
__global__ __launch_bounds__(256, 3) void hat_gemm(const float* __restrict__ item,
                                                   const ushort* __restrict__ whi,
                                                   const ushort* __restrict__ wlo,
                                                   float* __restrict__ hat,
                                                   int b0, int nbt2) {
    __shared__ ushort lds[2 * 128 * LDK];     // 36,864 B: Wh | Wl (one K-half)
    ushort* Wh = lds;
    ushort* Wl = lds + 128 * LDK;
    float*  ef = (float*)lds;                 // 64 x LDEF fp32 = 33,792 B aliased

    const int blk = blockIdx.x;
    const int s   = blk / nbt2;               // s-major
    const int btm = blk % nbt2;               // 64-row batch tile
    const int t   = threadIdx.x;

    const int wave = t >> 6, lane = t & 63;
    const int wm = wave >> 1, wn = wave & 1;  // wm: 32-row half, wn: 64-col half
    const int m0 = lane & 15, q = lane >> 4;

    // ---- A: load fp32, split once, fully resident (16 short8 = 64 VGPR) ----
    short8 ah[2][2][2], al[2][2][2];          // [st][kk][tm]
    {
        const float* ib = item +
            ((size_t)(b0 + btm * 64 + wm * 32 + m0) * SDIM + s) * HDIM;
        #pragma unroll
        for (int tm = 0; tm < 2; ++tm) {
            const float* p = ib + (size_t)(tm * 16) * (SDIM * HDIM);
            #pragma unroll
            for (int st = 0; st < 2; ++st)
                #pragma unroll
                for (int kk = 0; kk < 2; ++kk) {
                    uint4 hi, lo;
                    split8(p + st * 64 + kk * 32 + q * 8, &hi, &lo);
                    ah[st][kk][tm] = __builtin_bit_cast(short8, hi);
                    al[st][kk][tm] = __builtin_bit_cast(short8, lo);
                }
        }
    }

    const size_t wbase = (size_t)s * (IDIM * HDIM) * HDIM;

    #pragma unroll 1
    for (int ii = 0; ii < IDIM; ++ii) {
        const ushort* whB = whi + wbase + (size_t)ii * HDIM * HDIM;
        const ushort* wlB = wlo + wbase + (size_t)ii * HDIM * HDIM;

        f32x4 acc[2][4];
        #pragma unroll
        for (int tm = 0; tm < 2; ++tm)
            #pragma unroll
            for (int tn = 0; tn < 4; ++tn)
                acc[tm][tn] = (f32x4){0.f, 0.f, 0.f, 0.f};

        #pragma unroll
        for (int st = 0; st < 2; ++st) {
            __syncthreads();                  // prev readers of Wh/Wl | ef done

            // ---- stage one 64-wide K-half of W: pure 16-B copies ----
            #pragma unroll
            for (int c = t; c < 2048; c += 256) {
                int a   = c >> 10;            // 0: hi, 1: lo (uniform per iter)
                int r   = c & 1023;
                int row = r >> 3, g = r & 7;
                const ushort* src = (a ? wlB : whB) +
                                    (size_t)row * HDIM + st * 64 + g * 8;
                ushort* dst = (a ? Wl : Wh) + row * LDK + g * 8;
                *(uint4*)dst = *(const uint4*)src;
            }
            __syncthreads();

            // ---- MFMA over this K-half; A from resident registers ----
            #pragma unroll
            for (int kk = 0; kk < 2; ++kk) {
                const int kof = kk * 32 + q * 8;
                short8 bh[4], bl[4];
                #pragma unroll
                for (int tn = 0; tn < 4; ++tn) {
                    int ro = (wn * 64 + tn * 16 + m0) * LDK + kof;
                    bh[tn] = *(const short8*)(&Wh[ro]);
                    bl[tn] = *(const short8*)(&Wl[ro]);
                }
                #pragma unroll
                for (int tm = 0; tm < 2; ++tm)
                    #pragma unroll
                    for (int tn = 0; tn < 4; ++tn) {
                        acc[tm][tn] = __builtin_amdgcn_mfma_f32_16x16x32_bf16(
                            ah[st][kk][tm], bl[tn], acc[tm][tn], 0, 0, 0);
                        acc[tm][tn] = __builtin_amdgcn_mfma_f32_16x16x32_bf16(
                            al[st][kk][tm], bh[tn], acc[tm][tn], 0, 0, 0);
                        acc[tm][tn] = __builtin_amdgcn_mfma_f32_16x16x32_bf16(
                            ah[st][kk][tm], bh[tn], acc[tm][tn], 0, 0, 0);
                    }
            }
        }

        // ---- epilogue: acc -> ef (64 rows, all waves) -> coalesced store ----
        __syncthreads();                      // MFMA LDS reads done
        #pragma unroll
        for (int tm = 0; tm < 2; ++tm) {
            #pragma unroll
            for (int tn = 0; tn < 4; ++tn) {
                int col = wn * 64 + tn * 16 + m0;
                #pragma unroll
                for (int rg = 0; rg < 4; ++rg) {
                    int row = wm * 32 + tm * 16 + q * 4 + rg;   // [0,64)
                    ef[row * LDEF + col] = acc[tm][tn][rg];
                }
            }
        }
        __syncthreads();
        #pragma unroll
        for (int c = t; c < 2048; c += 256) {            // 64 rows x 32 float4
            int row = c >> 5, cc = c & 31;
            int bl_ = btm * 64 + row;
            float4 v = *(const float4*)(&ef[row * LDEF + cc * 4]);
            *(float4*)(hat + (((size_t)bl_ * IDIM + ii) * SDIM + s) * HDIM + cc * 4) = v;
        }
    }
}

// ---------------------------------------------------------------------------
// Kernel 2 (R6, unchanged): routing, 512 threads/block, pf[13] registers.
// ---------------------------------------------------------------------------
__global__ __launch_bounds__(512) void routing4(const float* __restrict__ hat,
                                                const int* __restrict__ mask,
                                                float* __restrict__ out, int b0) {
    __shared__ float cw[SDIM];
    __shared__ float eall[SDIM];
    __shared__ float ew[SDIM];
    __shared__ float icp[16 * HDIM];
    __shared__ float ic[HDIM];
    __shared__ float icf[HDIM];
    __shared__ int   mk[SDIM];

    const int blk = blockIdx.x;
    const int bl = blk >> 2, ii = blk & 3;
    const int b = b0 + bl;
    const int t = threadIdx.x, lane = t & 63, wv = t >> 6;
    const int hq = (t & 31) * 4;
    const int sg = t >> 5;                    // [0,16)
    const bool has13 = (sg < 8);
    const float* base = hat + ((size_t)bl * IDIM + ii) * (SDIM * HDIM);

    if (t < SDIM) mk[t] = mask[(size_t)b * SDIM + t];

    float4 pf[13];
    #pragma unroll
    for (int j = 0; j < 12; ++j)
        pf[j] = *(const float4*)(base + (size_t)(sg + 16 * j) * HDIM + hq);
    pf[12] = has13 ? *(const float4*)(base + (size_t)(sg + 192) * HDIM + hq)
                   : (float4){0.f, 0.f, 0.f, 0.f};
    __syncthreads();

    {
        float4 u = {0.f, 0.f, 0.f, 0.f};
        #pragma unroll
        for (int j = 0; j < 12; ++j) {
            if (mk[sg + 16 * j]) {
                u.x += pf[j].x; u.y += pf[j].y; u.z += pf[j].z; u.w += pf[j].w;
            }
        }
        if (has13 && mk[sg + 192]) {
            u.x += pf[12].x; u.y += pf[12].y; u.z += pf[12].z; u.w += pf[12].w;
        }
        *(float4*)(&icp[sg * HDIM + hq]) = u;
    }
    __syncthreads();
    if (t < HDIM) {
        float v = 0.f;
        #pragma unroll
        for (int g = 0; g < 16; ++g) v += icp[g * HDIM + t];
        ic[t] = v * (1.0f / 200.0f);
    }
    __syncthreads();
    if (wv == 0) {
        float i0 = ic[lane], i1 = ic[lane + 64];
        float p = i0 * i0 + i1 * i1;
        #pragma unroll
        for (int off = 32; off > 0; off >>= 1) p += __shfl_xor(p, off);
        float fac = p / (1.0f + p) / sqrtf(p + 1e-9f);
        icf[lane] = i0 * fac;
        icf[lane + 64] = i1 * fac;
    }
    __syncthreads();

    for (int iter = 1; iter <= 2; ++iter) {
        float4 c4 = *(const float4*)(&icf[hq]);
        #pragma unroll
        for (int j = 0; j < 13; ++j) {
            float d = fmaf(pf[j].x, c4.x, fmaf(pf[j].y, c4.y,
                      fmaf(pf[j].z, c4.z, pf[j].w * c4.w)));
            d += __shfl_xor(d, 16);
            d += __shfl_xor(d, 8);
            d += __shfl_xor(d, 4);
            d += __shfl_xor(d, 2);
            d += __shfl_xor(d, 1);
            if ((t & 31) == 0 && (j < 12 || has13)) {
                int s = sg + 16 * j;
                cw[s] = (iter == 1) ? d : cw[s] + d;
            }
        }
        __syncthreads();

        float m = fmaxf(cw[lane], fmaxf(cw[lane + 64], cw[lane + 128]));
        if (lane < SDIM - 192) m = fmaxf(m, cw[lane + 192]);
        #pragma unroll
        for (int off = 32; off > 0; off >>= 1) m = fmaxf(m, __shfl_xor(m, off));
        if (t < SDIM) {
            float e = __expf(cw[t] - m);
            eall[t] = e;
            ew[t] = mk[t] ? e : 0.0f;
        }
        __syncthreads();

        float D = eall[lane] + eall[lane + 64] + eall[lane + 128]
                + ((lane < SDIM - 192) ? eall[lane + 192] : 0.0f);
        #pragma unroll
        for (int off = 32; off > 0; off >>= 1) D += __shfl_xor(D, off);

        {
            float4 u = {0.f, 0.f, 0.f, 0.f};
            #pragma unroll
            for (int j = 0; j < 12; ++j) {
                float wgt = ew[sg + 16 * j];
                u.x = fmaf(wgt, pf[j].x, u.x);
                u.y = fmaf(wgt, pf[j].y, u.y);
                u.z = fmaf(wgt, pf[j].z, u.z);
                u.w = fmaf(wgt, pf[j].w, u.w);
            }
            float wgt = has13 ? ew[sg + 192] : 0.0f;
            u.x = fmaf(wgt, pf[12].x, u.x);
            u.y = fmaf(wgt, pf[12].y, u.y);
            u.z = fmaf(wgt, pf[12].z, u.z);
            u.w = fmaf(wgt, pf[12].w, u.w);
            *(float4*)(&icp[sg * HDIM + hq]) = u;
        }
        __syncthreads();

        if (t < HDIM) {
            float v = 0.f;
            #pragma unroll
            for (int g = 0; g < 16; ++g) v += icp[g * HDIM + t];
            ic[t] = v / D;
        }
        __syncthreads();

        if (wv == 0) {
            float i0 = ic[lane], i1 = ic[lane + 64];
            float p = i0 * i0 + i1 * i1;
            #pragma unroll
            for (int off = 32; off > 0; off >>= 1) p += __shfl_xor(p, off);
            float fac = p / (1.0f + p) / sqrtf(p + 1e-9f);
            if (iter == 1) {
                icf[lane] = i0 * fac;
                icf[lane + 64] = i1 * fac;
            } else {
                out[((size_t)b * IDIM + ii) * HDIM + lane]      = i0 * fac;
                out[((size_t)b * IDIM + ii) * HDIM + lane + 64] = i1 * fac;
            }
        }
        if (iter == 1) __syncthreads();
    }
}

extern "C" void kernel_launch(void* const* d_in, const int* in_sizes, int n_in,
                              void* d_out, int out_size, void* d_ws, size_t ws_size,
                              hipStream_t stream) {
    const float* item = nullptr;
    const int*   msk  = nullptr;
    const float* w    = nullptr;
    for (int i = 0; i < n_in; ++i) {
        if (in_sizes[i] == BDIM * SDIM * HDIM)             item = (const float*)d_in[i];
        else if (in_sizes[i] == BDIM * SDIM)               msk  = (const int*)d_in[i];
        else if (in_sizes[i] == SDIM * IDIM * HDIM * HDIM) w    = (const float*)d_in[i];
    }
    if (!item) item = (const float*)d_in[0];
    if (!msk)  msk  = (const int*)d_in[1];
    if (!w)    w    = (const float*)d_in[2];

    // ws layout: [w_hi 26.2 MB][w_lo 26.2 MB][hat chunk]
    const size_t wElems   = (size_t)SDIM * IDIM * HDIM * HDIM;
    const size_t wSplitB  = wElems * sizeof(ushort);              // 26,214,400
    ushort* w_hi = (ushort*)d_ws;
    ushort* w_lo = (ushort*)((char*)d_ws + wSplitB);
    float*  hat  = (float*)((char*)d_ws + 2 * wSplitB);
    float*  out  = (float*)d_out;

    wsplit<<<2048, 256, 0, stream>>>(w, w_hi, w_lo);

    const size_t perB = (size_t)IDIM * SDIM * HDIM * sizeof(float);
    size_t hatCap = (ws_size - 2 * wSplitB) / perB;
    int chunk = 512;
    if (hatCap < (size_t)chunk) chunk = (int)((hatCap / 128) * 128);
    if (chunk < 128) chunk = 128;
    for (int bb = 0; bb < BDIM; bb += chunk) {
        int cb = (BDIM - bb < chunk) ? (BDIM - bb) : chunk;
        int nbt2 = cb / 64;
        hat_gemm<<<SDIM * nbt2, 256, 0, stream>>>(item, w_hi, w_lo, hat, bb, nbt2);
        routing4<<<cb * IDIM, 512, 0, stream>>>(hat, msk, out, bb);
    }
}

// Round 5
// 510.602 us; speedup vs baseline: 1.5041x; 1.2048x over previous
//
#include <hip/hip_runtime.h>
#include <hip/hip_bf16.h>
#include <cstdint>

#define SDIM 200
#define HDIM 128
#define IDIM 4
#define BDIM 1024
#define LDK 72            // bf16 leading dim per 64-wide K-half (144 B rows)
#define REG_US 9216       // 128*LDK ushorts per subregion (hi or lo, one K-half)
#define HALF_US 18432     // ushorts per K-half image (hi+lo) = 36,864 B
#define IMG_US 36864      // ushorts per (s,ii) full image = 73,728 B

typedef __attribute__((ext_vector_type(8))) short short8;
typedef __attribute__((ext_vector_type(4))) float f32x4;

__device__ __forceinline__ ushort f32_to_bf16u(float f) {
    uint32_t u = __builtin_bit_cast(uint32_t, f);
    u += 0x7FFFu + ((u >> 16) & 1u);   // RNE
    return (ushort)(u >> 16);
}
__device__ __forceinline__ float bf16u_to_f32(ushort h) {
    uint32_t u = ((uint32_t)h) << 16;
    return __builtin_bit_cast(float, u);
}
__device__ __forceinline__ void split8(const float* p, uint4* hi, uint4* lo) {
    union { ushort u[8]; uint4 v; } xh, xl;
    #pragma unroll
    for (int j = 0; j < 8; ++j) {
        float f = p[j];
        ushort h = f32_to_bf16u(f);
        float r = f - bf16u_to_f32(h);
        xh.u[j] = h;
        xl.u[j] = f32_to_bf16u(r);
    }
    *hi = xh.v; *lo = xl.v;
}

// ---------------------------------------------------------------------------
// Kernel 0 (R8): W prepass -> exact LDS images. Per (s,ii): 73,728 B image:
//   [Wh0 | Wl0 | Wh1 | Wl1], each 128 rows x LDK(72) ushorts, pad zeroed.
// Hot-kernel staging becomes a flat memcpy (zero VALU, zero layout math).
// ---------------------------------------------------------------------------
__global__ __launch_bounds__(256) void wstage(const float* __restrict__ w,
                                              ushort* __restrict__ img) {
    const int blk = blockIdx.x;            // 800 = (s<<2) | ii
    const int s = blk >> 2, ii = blk & 3;
    const int t = threadIdx.x;
    const float* wB = w + ((size_t)s * (IDIM * HDIM) + (size_t)ii * HDIM) * HDIM;
    ushort* dst = img + (size_t)blk * IMG_US;

    for (int g = t; g < 2048; g += 256) {  // 8-elem groups, row-major linear
        uint4 hi, lo;
        split8(wB + (size_t)g * 8, &hi, &lo);
        int c0 = g >> 4;                   // output col (B-row) 0..127
        int st = (g >> 3) & 1;             // K-half
        int kl = (g & 7) * 8;              // k offset within half, 0..56
        *(uint4*)(dst + st * HALF_US +          c0 * LDK + kl) = hi;
        *(uint4*)(dst + st * HALF_US + REG_US + c0 * LDK + kl) = lo;
    }
    for (int p = t; p < 4096; p += 256) {  // zero pads [64..72) in 4 subregions
        int rg = p >> 10, c0 = (p >> 3) & 127, o = p & 7;
        dst[rg * REG_US + c0 * LDK + 64 + o] = 0;
    }
}

// ---------------------------------------------------------------------------
// Kernel 1 (R8): ii-merged hat GEMM, M=128, half-K W staging (LDS 36,864 B ->
// 4 blocks/CU; all 800 blocks/chunk co-resident). W staged via flat uint4 copy
// of prepass image; A load+split per block (compiler remat from L2 is clean,
// R5-proven). Direct acc->global stores (no ef transpose, no launch_bounds min
// -> no spill). Grid bt-major: XCD = s%8, same-s blocks share img in L2.
// ---------------------------------------------------------------------------
__global__ __launch_bounds__(256) void hat_gemm(const float* __restrict__ item,
                                                const ushort* __restrict__ img,
                                                float* __restrict__ hat,
                                                int b0) {
    __shared__ ushort lds[HALF_US];        // 36,864 B: one K-half image (hi|lo)

    const int blk = blockIdx.x;
    const int bt = blk / SDIM;
    const int s  = blk % SDIM;
    const int t  = threadIdx.x;
    const int wave = t >> 6, lane = t & 63;
    const int wm = wave >> 1, wn = wave & 1;
    const int m0 = lane & 15, q = lane >> 4;

    // ---- A: load fp32 + split (R5-proven; compiler remats from L2 as needed)
    short8 ah[2][2][4], al[2][2][4];       // [st][kk][tm]
    const float* ib = item +
        ((size_t)(b0 + bt * 128 + wm * 64 + m0) * SDIM + s) * HDIM;
    #pragma unroll
    for (int tm = 0; tm < 4; ++tm) {
        const float* p = ib + (size_t)(tm * 16) * (SDIM * HDIM);
        #pragma unroll
        for (int st = 0; st < 2; ++st)
            #pragma unroll
            for (int kk = 0; kk < 2; ++kk) {
                uint4 hi, lo;
                split8(p + st * 64 + kk * 32 + q * 8, &hi, &lo);
                ah[st][kk][tm] = __builtin_bit_cast(short8, hi);
                al[st][kk][tm] = __builtin_bit_cast(short8, lo);
            }
    }

    const ushort* imgS = img + (size_t)(s * IDIM) * IMG_US;

    #pragma unroll 1
    for (int ii = 0; ii < IDIM; ++ii) {
        const ushort* wimg = imgS + (size_t)ii * IMG_US;

        f32x4 acc[4][4];
        #pragma unroll
        for (int tm = 0; tm < 4; ++tm)
            #pragma unroll
            for (int tn = 0; tn < 4; ++tn)
                acc[tm][tn] = (f32x4){0.f, 0.f, 0.f, 0.f};

        #pragma unroll
        for (int st = 0; st < 2; ++st) {
            __syncthreads();               // prior half's LDS reads done

            // ---- stage one K-half image: flat memcpy, 9 uint4 per thread
            {
                const uint4* src = (const uint4*)(wimg + (size_t)st * HALF_US);
                uint4* dstl = (uint4*)lds;
                #pragma unroll
                for (int k = 0; k < 9; ++k)
                    dstl[t + 256 * k] = src[t + 256 * k];
            }
            __syncthreads();

            const ushort* Wh = lds;
            const ushort* Wl = lds + REG_US;
            #pragma unroll
            for (int kk = 0; kk < 2; ++kk) {
                const int kof = kk * 32 + q * 8;
                short8 bh[4], bl[4];
                #pragma unroll
                for (int tn = 0; tn < 4; ++tn) {
                    int ro = (wn * 64 + tn * 16 + m0) * LDK + kof;
                    bh[tn] = *(const short8*)(&Wh[ro]);
                    bl[tn] = *(const short8*)(&Wl[ro]);
                }
                #pragma unroll
                for (int tm = 0; tm < 4; ++tm)
                    #pragma unroll
                    for (int tn = 0; tn < 4; ++tn) {
                        acc[tm][tn] = __builtin_amdgcn_mfma_f32_16x16x32_bf16(
                            ah[st][kk][tm], bl[tn], acc[tm][tn], 0, 0, 0);
                        acc[tm][tn] = __builtin_amdgcn_mfma_f32_16x16x32_bf16(
                            al[st][kk][tm], bh[tn], acc[tm][tn], 0, 0, 0);
                        acc[tm][tn] = __builtin_amdgcn_mfma_f32_16x16x32_bf16(
                            ah[st][kk][tm], bh[tn], acc[tm][tn], 0, 0, 0);
                    }
            }
        }

        // ---- direct store: 16 lanes x 16 cols = 64-B row segments, L2-merged
        #pragma unroll
        for (int tm = 0; tm < 4; ++tm) {
            #pragma unroll
            for (int tn = 0; tn < 4; ++tn) {
                const int col = wn * 64 + tn * 16 + m0;
                #pragma unroll
                for (int rg = 0; rg < 4; ++rg) {
                    const size_t bl_ = (size_t)(bt * 128 + wm * 64 + tm * 16 + q * 4 + rg);
                    hat[((bl_ * IDIM + ii) * SDIM + s) * HDIM + col] = acc[tm][tn][rg];
                }
            }
        }
    }
}

// ---------------------------------------------------------------------------
// Kernel 2 (R8): routing, 512 thr, barriers 15 -> 8. Exp/denominator/merge/
// squash phases are all-thread-redundant (recompute instead of LDS round-trip)
// -> no idle-wave serial sections between barriers. Arithmetic order preserved.
// ---------------------------------------------------------------------------
__global__ __launch_bounds__(512) void routing4(const float* __restrict__ hat,
                                                const int* __restrict__ mask,
                                                float* __restrict__ out, int b0) {
    __shared__ float cw[SDIM];
    __shared__ float icp[16 * HDIM];
    __shared__ float icf[HDIM];
    __shared__ int   mk[SDIM];

    const int blk = blockIdx.x;
    const int bl = blk >> 2, ii = blk & 3;
    const int b = b0 + bl;
    const int t = threadIdx.x, lane = t & 63, wv = t >> 6;
    const int hq = (t & 31) * 4;
    const int sg = t >> 5;                 // [0,16)
    const bool has13 = (sg < 8);
    const float* base = hat + ((size_t)bl * IDIM + ii) * (SDIM * HDIM);

    if (t < SDIM) mk[t] = mask[(size_t)b * SDIM + t];

    float4 pf[13];
    #pragma unroll
    for (int j = 0; j < 12; ++j)
        pf[j] = *(const float4*)(base + (size_t)(sg + 16 * j) * HDIM + hq);
    pf[12] = has13 ? *(const float4*)(base + (size_t)(sg + 192) * HDIM + hq)
                   : (float4){0.f, 0.f, 0.f, 0.f};
    __syncthreads();                       // mk ready                     [B1]

    // ---- pass 0: uniform sw = 1/200, masked numerator
    {
        float4 u = {0.f, 0.f, 0.f, 0.f};
        #pragma unroll
        for (int j = 0; j < 12; ++j) {
            if (mk[sg + 16 * j]) {
                u.x += pf[j].x; u.y += pf[j].y; u.z += pf[j].z; u.w += pf[j].w;
            }
        }
        if (has13 && mk[sg + 192]) {
            u.x += pf[12].x; u.y += pf[12].y; u.z += pf[12].z; u.w += pf[12].w;
        }
        *(float4*)(&icp[sg * HDIM + hq]) = u;
    }
    __syncthreads();                       // icp ready                    [B2]
    {
        float i0 = 0.f, i1 = 0.f;
        #pragma unroll
        for (int g = 0; g < 16; ++g) {
            i0 += icp[g * HDIM + lane];
            i1 += icp[g * HDIM + lane + 64];
        }
        i0 *= (1.0f / 200.0f);
        i1 *= (1.0f / 200.0f);
        float p = i0 * i0 + i1 * i1;
        #pragma unroll
        for (int off = 32; off > 0; off >>= 1) p += __shfl_xor(p, off);
        float fac = p / (1.0f + p) / sqrtf(p + 1e-9f);
        if (wv == 0) {
            icf[lane] = i0 * fac;
            icf[lane + 64] = i1 * fac;
        }
    }
    __syncthreads();                       // icf ready                    [B3]

    for (int iter = 1; iter <= 2; ++iter) {
        // A: delta[s] = <hat_s, icf>
        float4 c4 = *(const float4*)(&icf[hq]);
        #pragma unroll
        for (int j = 0; j < 13; ++j) {
            float d = fmaf(pf[j].x, c4.x, fmaf(pf[j].y, c4.y,
                      fmaf(pf[j].z, c4.z, pf[j].w * c4.w)));
            d += __shfl_xor(d, 16);
            d += __shfl_xor(d, 8);
            d += __shfl_xor(d, 4);
            d += __shfl_xor(d, 2);
            d += __shfl_xor(d, 1);
            if ((t & 31) == 0 && (j < 12 || has13)) {
                int s = sg + 16 * j;
                cw[s] = (iter == 1) ? d : cw[s] + d;
            }
        }
        __syncthreads();                   // cw ready                 [B4/B6]

        // merged: max, denominator, own-exps, numerator (all threads)
        float m = fmaxf(cw[lane], fmaxf(cw[lane + 64], cw[lane + 128]));
        if (lane < SDIM - 192) m = fmaxf(m, cw[lane + 192]);
        #pragma unroll
        for (int off = 32; off > 0; off >>= 1) m = fmaxf(m, __shfl_xor(m, off));

        float D = __expf(cw[lane] - m) + __expf(cw[lane + 64] - m)
                + __expf(cw[lane + 128] - m)
                + ((lane < SDIM - 192) ? __expf(cw[lane + 192] - m) : 0.0f);
        #pragma unroll
        for (int off = 32; off > 0; off >>= 1) D += __shfl_xor(D, off);

        {
            float4 u = {0.f, 0.f, 0.f, 0.f};
            #pragma unroll
            for (int j = 0; j < 12; ++j) {
                int s = sg + 16 * j;
                float wgt = mk[s] ? __expf(cw[s] - m) : 0.0f;
                u.x = fmaf(wgt, pf[j].x, u.x);
                u.y = fmaf(wgt, pf[j].y, u.y);
                u.z = fmaf(wgt, pf[j].z, u.z);
                u.w = fmaf(wgt, pf[j].w, u.w);
            }
            float wgt = (has13 && mk[sg + 192]) ? __expf(cw[sg + 192] - m) : 0.0f;
            u.x = fmaf(wgt, pf[12].x, u.x);
            u.y = fmaf(wgt, pf[12].y, u.y);
            u.z = fmaf(wgt, pf[12].z, u.z);
            u.w = fmaf(wgt, pf[12].w, u.w);
            *(float4*)(&icp[sg * HDIM + hq]) = u;
        }
        __syncthreads();                   // icp ready                [B5/B7]

        // merged: 16-way merge, /D, squash (all threads redundant)
        {
            float i0 = 0.f, i1 = 0.f;
            #pragma unroll
            for (int g = 0; g < 16; ++g) {
                i0 += icp[g * HDIM + lane];
                i1 += icp[g * HDIM + lane + 64];
            }
            i0 /= D;
            i1 /= D;
            float p = i0 * i0 + i1 * i1;
            #pragma unroll
            for (int off = 32; off > 0; off >>= 1) p += __shfl_xor(p, off);
            float fac = p / (1.0f + p) / sqrtf(p + 1e-9f);
            if (iter == 1) {
                if (wv == 0) {
                    icf[lane] = i0 * fac;
                    icf[lane + 64] = i1 * fac;
                }
            } else {
                if (wv == 0) {
                    out[((size_t)b * IDIM + ii) * HDIM + lane]      = i0 * fac;
                    out[((size_t)b * IDIM + ii) * HDIM + lane + 64] = i1 * fac;
                }
            }
        }
        if (iter == 1) __syncthreads();    // icf ready                   [B8]
    }
}

extern "C" void kernel_launch(void* const* d_in, const int* in_sizes, int n_in,
                              void* d_out, int out_size, void* d_ws, size_t ws_size,
                              hipStream_t stream) {
    const float* item = nullptr;
    const int*   msk  = nullptr;
    const float* w    = nullptr;
    for (int i = 0; i < n_in; ++i) {
        if (in_sizes[i] == BDIM * SDIM * HDIM)             item = (const float*)d_in[i];
        else if (in_sizes[i] == BDIM * SDIM)               msk  = (const int*)d_in[i];
        else if (in_sizes[i] == SDIM * IDIM * HDIM * HDIM) w    = (const float*)d_in[i];
    }
    if (!item) item = (const float*)d_in[0];
    if (!msk)  msk  = (const int*)d_in[1];
    if (!w)    w    = (const float*)d_in[2];

    // ws layout: [w images 58.98 MB][hat chunk 209.7 MB]
    const size_t imgBytes = (size_t)SDIM * IDIM * IMG_US * sizeof(ushort);
    ushort* wimg = (ushort*)d_ws;
    float*  hat  = (float*)((char*)d_ws + imgBytes);
    float*  out  = (float*)d_out;

    wstage<<<SDIM * IDIM, 256, 0, stream>>>(w, wimg);

    const size_t perB = (size_t)IDIM * SDIM * HDIM * sizeof(float);
    size_t hatCap = (ws_size - imgBytes) / perB;
    int chunk = 512;
    if (hatCap < (size_t)chunk) chunk = (int)((hatCap / 128) * 128);
    if (chunk < 128) chunk = 128;
    for (int bb = 0; bb < BDIM; bb += chunk) {
        int cb = (BDIM - bb < chunk) ? (BDIM - bb) : chunk;
        int nbt = cb / 128;
        hat_gemm<<<nbt * SDIM, 256, 0, stream>>>(item, wimg, hat, bb);
        routing4<<<cb * IDIM, 512, 0, stream>>>(hat, msk, out, bb);
    }
}

// Round 6
// 495.904 us; speedup vs baseline: 1.5487x; 1.0296x over previous
//
#include <hip/hip_runtime.h>
#include <hip/hip_bf16.h>
#include <cstdint>

#define SDIM 200
#define HDIM 128
#define IDIM 4
#define BDIM 1024
#define LDK 72            // bf16 leading dim per 64-wide K-half (144 B rows)
#define REG_US 9216       // 128*LDK ushorts per subregion (hi or lo, one K-half)
#define HALF_US 18432     // ushorts per K-half image (hi+lo) = 36,864 B
#define IMG_US 36864      // ushorts per (s,ii) full image = 73,728 B

typedef __attribute__((ext_vector_type(8))) short short8;
typedef __attribute__((ext_vector_type(4))) float f32x4;

__device__ __forceinline__ ushort f32_to_bf16u(float f) {
    uint32_t u = __builtin_bit_cast(uint32_t, f);
    u += 0x7FFFu + ((u >> 16) & 1u);   // RNE
    return (ushort)(u >> 16);
}
__device__ __forceinline__ float bf16u_to_f32(ushort h) {
    uint32_t u = ((uint32_t)h) << 16;
    return __builtin_bit_cast(float, u);
}
__device__ __forceinline__ void split8(const float* p, uint4* hi, uint4* lo) {
    union { ushort u[8]; uint4 v; } xh, xl;
    #pragma unroll
    for (int j = 0; j < 8; ++j) {
        float f = p[j];
        ushort h = f32_to_bf16u(f);
        float r = f - bf16u_to_f32(h);
        xh.u[j] = h;
        xl.u[j] = f32_to_bf16u(r);
    }
    *hi = xh.v; *lo = xl.v;
}

// async global->LDS, 16 B per lane; LDS dest = wave-uniform base + lane*16
__device__ __forceinline__ void gload16(const void* g, void* l) {
    __builtin_amdgcn_global_load_lds(
        (const __attribute__((address_space(1))) void*)g,
        (__attribute__((address_space(3))) void*)l,
        16, 0, 0);
}

// ---------------------------------------------------------------------------
// Kernel 0 (R9): W prepass -> exact LDS images. Per (s,ii): 73,728 B image:
//   [Wh0 | Wl0 | Wh1 | Wl1], each 128 rows x LDK(72) ushorts, pad zeroed.
// Pad-zeroing now uint4 (was scalar ushort: 6.5 MB of 2-B scattered stores).
// ---------------------------------------------------------------------------
__global__ __launch_bounds__(256) void wstage(const float* __restrict__ w,
                                              ushort* __restrict__ img) {
    const int blk = blockIdx.x;            // 800 = (s<<2) | ii
    const int s = blk >> 2, ii = blk & 3;
    const int t = threadIdx.x;
    const float* wB = w + ((size_t)s * (IDIM * HDIM) + (size_t)ii * HDIM) * HDIM;
    ushort* dst = img + (size_t)blk * IMG_US;

    for (int g = t; g < 2048; g += 256) {  // 8-elem groups, row-major linear
        uint4 hi, lo;
        split8(wB + (size_t)g * 8, &hi, &lo);
        int c0 = g >> 4;                   // output col (B-row) 0..127
        int st = (g >> 3) & 1;             // K-half
        int kl = (g & 7) * 8;              // k offset within half, 0..56
        *(uint4*)(dst + st * HALF_US +          c0 * LDK + kl) = hi;
        *(uint4*)(dst + st * HALF_US + REG_US + c0 * LDK + kl) = lo;
    }
    const uint4 z = {0u, 0u, 0u, 0u};      // zero pads [64..72) per row, 16 B
    for (int p = t; p < 512; p += 256) {
        int rg = p >> 7, c0 = p & 127;
        *(uint4*)(dst + rg * REG_US + c0 * LDK + 64) = z;
    }
}

// ---------------------------------------------------------------------------
// Kernel 1 (R9): ii-merged hat GEMM, async 2-buffer pipeline.
// 8 stages (k = ii*2 + st); stage k image = imgS + k*HALF_US (prepass is a
// flat LDS image -> global_load_lds width 16, zero address math).
// Per stage: issue STAGE(k+1) -> MFMA(buf[k&1]) -> barrier (vmcnt drain
// overlaps loads with MFMA; guide's minimal 2-phase pattern).
// LDS 73,728 B -> 2 blocks/CU. A split kept R8-style (FETCH-clean remat).
// ---------------------------------------------------------------------------
__global__ __launch_bounds__(256) void hat_gemm(const float* __restrict__ item,
                                                const ushort* __restrict__ img,
                                                float* __restrict__ hat,
                                                int b0) {
    __shared__ ushort lds[2 * HALF_US];    // 73,728 B: two K-half buffers

    const int blk = blockIdx.x;
    const int bt = blk / SDIM;
    const int s  = blk % SDIM;
    const int t  = threadIdx.x;
    const int wave = t >> 6, lane = t & 63;
    const int wm = wave >> 1, wn = wave & 1;
    const int m0 = lane & 15, q = lane >> 4;

    const ushort* imgS = img + (size_t)(s * IDIM) * IMG_US;

    // stage one K-half image (36,864 B): 9 x 1KB waves-worth of 16-B DMA
    #define STAGE(dstbuf, srcp)                                            \
        {                                                                  \
            const char* _s = (const char*)(srcp);                          \
            char* _d = (char*)(dstbuf);                                    \
            _Pragma("unroll")                                              \
            for (int _i = 0; _i < 9; ++_i) {                               \
                const int _off = (_i * 256 + wave * 64) * 16;              \
                gload16(_s + _off + lane * 16, _d + _off);                 \
            }                                                              \
        }

    // ---- prologue: kick stage 0 DMA, then A load+split under it ----
    STAGE(lds, imgS);

    short8 ah[2][2][4], al[2][2][4];       // [st][kk][tm]
    {
        const float* ib = item +
            ((size_t)(b0 + bt * 128 + wm * 64 + m0) * SDIM + s) * HDIM;
        #pragma unroll
        for (int tm = 0; tm < 4; ++tm) {
            const float* p = ib + (size_t)(tm * 16) * (SDIM * HDIM);
            #pragma unroll
            for (int st = 0; st < 2; ++st)
                #pragma unroll
                for (int kk = 0; kk < 2; ++kk) {
                    uint4 hi, lo;
                    split8(p + st * 64 + kk * 32 + q * 8, &hi, &lo);
                    ah[st][kk][tm] = __builtin_bit_cast(short8, hi);
                    al[st][kk][tm] = __builtin_bit_cast(short8, lo);
                }
        }
    }
    __syncthreads();                       // stage 0 (and A loads) complete

    f32x4 acc[4][4];

    #pragma unroll
    for (int k = 0; k < 8; ++k) {
        const int ii = k >> 1, st = k & 1;

        if (st == 0) {
            #pragma unroll
            for (int tm = 0; tm < 4; ++tm)
                #pragma unroll
                for (int tn = 0; tn < 4; ++tn)
                    acc[tm][tn] = (f32x4){0.f, 0.f, 0.f, 0.f};
        }

        if (k < 7)
            STAGE(lds + ((k + 1) & 1) * HALF_US, imgS + (size_t)(k + 1) * HALF_US);

        const ushort* Wh = lds + (k & 1) * HALF_US;
        const ushort* Wl = Wh + REG_US;
        #pragma unroll
        for (int kk = 0; kk < 2; ++kk) {
            const int kof = kk * 32 + q * 8;
            short8 bh[4], bl[4];
            #pragma unroll
            for (int tn = 0; tn < 4; ++tn) {
                int ro = (wn * 64 + tn * 16 + m0) * LDK + kof;
                bh[tn] = *(const short8*)(&Wh[ro]);
                bl[tn] = *(const short8*)(&Wl[ro]);
            }
            #pragma unroll
            for (int tm = 0; tm < 4; ++tm)
                #pragma unroll
                for (int tn = 0; tn < 4; ++tn) {
                    acc[tm][tn] = __builtin_amdgcn_mfma_f32_16x16x32_bf16(
                        ah[st][kk][tm], bl[tn], acc[tm][tn], 0, 0, 0);
                    acc[tm][tn] = __builtin_amdgcn_mfma_f32_16x16x32_bf16(
                        al[st][kk][tm], bh[tn], acc[tm][tn], 0, 0, 0);
                    acc[tm][tn] = __builtin_amdgcn_mfma_f32_16x16x32_bf16(
                        ah[st][kk][tm], bh[tn], acc[tm][tn], 0, 0, 0);
                }
        }

        if (st == 1) {                     // direct acc -> hat stores
            #pragma unroll
            for (int tm = 0; tm < 4; ++tm) {
                #pragma unroll
                for (int tn = 0; tn < 4; ++tn) {
                    const int col = wn * 64 + tn * 16 + m0;
                    #pragma unroll
                    for (int rg = 0; rg < 4; ++rg) {
                        const size_t bl_ =
                            (size_t)(bt * 128 + wm * 64 + tm * 16 + q * 4 + rg);
                        hat[((bl_ * IDIM + ii) * SDIM + s) * HDIM + col] =
                            acc[tm][tn][rg];
                    }
                }
            }
        }

        if (k < 7) __syncthreads();        // stage k+1 landed; buf reads done
    }
    #undef STAGE
}

// ---------------------------------------------------------------------------
// Kernel 2 (R8, unchanged): routing, 512 thr, 8 barriers, redundant phases.
// ---------------------------------------------------------------------------
__global__ __launch_bounds__(512) void routing4(const float* __restrict__ hat,
                                                const int* __restrict__ mask,
                                                float* __restrict__ out, int b0) {
    __shared__ float cw[SDIM];
    __shared__ float icp[16 * HDIM];
    __shared__ float icf[HDIM];
    __shared__ int   mk[SDIM];

    const int blk = blockIdx.x;
    const int bl = blk >> 2, ii = blk & 3;
    const int b = b0 + bl;
    const int t = threadIdx.x, lane = t & 63, wv = t >> 6;
    const int hq = (t & 31) * 4;
    const int sg = t >> 5;                 // [0,16)
    const bool has13 = (sg < 8);
    const float* base = hat + ((size_t)bl * IDIM + ii) * (SDIM * HDIM);

    if (t < SDIM) mk[t] = mask[(size_t)b * SDIM + t];

    float4 pf[13];
    #pragma unroll
    for (int j = 0; j < 12; ++j)
        pf[j] = *(const float4*)(base + (size_t)(sg + 16 * j) * HDIM + hq);
    pf[12] = has13 ? *(const float4*)(base + (size_t)(sg + 192) * HDIM + hq)
                   : (float4){0.f, 0.f, 0.f, 0.f};
    __syncthreads();                       // mk ready                     [B1]

    {
        float4 u = {0.f, 0.f, 0.f, 0.f};
        #pragma unroll
        for (int j = 0; j < 12; ++j) {
            if (mk[sg + 16 * j]) {
                u.x += pf[j].x; u.y += pf[j].y; u.z += pf[j].z; u.w += pf[j].w;
            }
        }
        if (has13 && mk[sg + 192]) {
            u.x += pf[12].x; u.y += pf[12].y; u.z += pf[12].z; u.w += pf[12].w;
        }
        *(float4*)(&icp[sg * HDIM + hq]) = u;
    }
    __syncthreads();                       // icp ready                    [B2]
    {
        float i0 = 0.f, i1 = 0.f;
        #pragma unroll
        for (int g = 0; g < 16; ++g) {
            i0 += icp[g * HDIM + lane];
            i1 += icp[g * HDIM + lane + 64];
        }
        i0 *= (1.0f / 200.0f);
        i1 *= (1.0f / 200.0f);
        float p = i0 * i0 + i1 * i1;
        #pragma unroll
        for (int off = 32; off > 0; off >>= 1) p += __shfl_xor(p, off);
        float fac = p / (1.0f + p) / sqrtf(p + 1e-9f);
        if (wv == 0) {
            icf[lane] = i0 * fac;
            icf[lane + 64] = i1 * fac;
        }
    }
    __syncthreads();                       // icf ready                    [B3]

    for (int iter = 1; iter <= 2; ++iter) {
        float4 c4 = *(const float4*)(&icf[hq]);
        #pragma unroll
        for (int j = 0; j < 13; ++j) {
            float d = fmaf(pf[j].x, c4.x, fmaf(pf[j].y, c4.y,
                      fmaf(pf[j].z, c4.z, pf[j].w * c4.w)));
            d += __shfl_xor(d, 16);
            d += __shfl_xor(d, 8);
            d += __shfl_xor(d, 4);
            d += __shfl_xor(d, 2);
            d += __shfl_xor(d, 1);
            if ((t & 31) == 0 && (j < 12 || has13)) {
                int s = sg + 16 * j;
                cw[s] = (iter == 1) ? d : cw[s] + d;
            }
        }
        __syncthreads();                   // cw ready                 [B4/B6]

        float m = fmaxf(cw[lane], fmaxf(cw[lane + 64], cw[lane + 128]));
        if (lane < SDIM - 192) m = fmaxf(m, cw[lane + 192]);
        #pragma unroll
        for (int off = 32; off > 0; off >>= 1) m = fmaxf(m, __shfl_xor(m, off));

        float D = __expf(cw[lane] - m) + __expf(cw[lane + 64] - m)
                + __expf(cw[lane + 128] - m)
                + ((lane < SDIM - 192) ? __expf(cw[lane + 192] - m) : 0.0f);
        #pragma unroll
        for (int off = 32; off > 0; off >>= 1) D += __shfl_xor(D, off);

        {
            float4 u = {0.f, 0.f, 0.f, 0.f};
            #pragma unroll
            for (int j = 0; j < 12; ++j) {
                int s = sg + 16 * j;
                float wgt = mk[s] ? __expf(cw[s] - m) : 0.0f;
                u.x = fmaf(wgt, pf[j].x, u.x);
                u.y = fmaf(wgt, pf[j].y, u.y);
                u.z = fmaf(wgt, pf[j].z, u.z);
                u.w = fmaf(wgt, pf[j].w, u.w);
            }
            float wgt = (has13 && mk[sg + 192]) ? __expf(cw[sg + 192] - m) : 0.0f;
            u.x = fmaf(wgt, pf[12].x, u.x);
            u.y = fmaf(wgt, pf[12].y, u.y);
            u.z = fmaf(wgt, pf[12].z, u.z);
            u.w = fmaf(wgt, pf[12].w, u.w);
            *(float4*)(&icp[sg * HDIM + hq]) = u;
        }
        __syncthreads();                   // icp ready                [B5/B7]

        {
            float i0 = 0.f, i1 = 0.f;
            #pragma unroll
            for (int g = 0; g < 16; ++g) {
                i0 += icp[g * HDIM + lane];
                i1 += icp[g * HDIM + lane + 64];
            }
            i0 /= D;
            i1 /= D;
            float p = i0 * i0 + i1 * i1;
            #pragma unroll
            for (int off = 32; off > 0; off >>= 1) p += __shfl_xor(p, off);
            float fac = p / (1.0f + p) / sqrtf(p + 1e-9f);
            if (iter == 1) {
                if (wv == 0) {
                    icf[lane] = i0 * fac;
                    icf[lane + 64] = i1 * fac;
                }
            } else {
                if (wv == 0) {
                    out[((size_t)b * IDIM + ii) * HDIM + lane]      = i0 * fac;
                    out[((size_t)b * IDIM + ii) * HDIM + lane + 64] = i1 * fac;
                }
            }
        }
        if (iter == 1) __syncthreads();    // icf ready                   [B8]
    }
}

extern "C" void kernel_launch(void* const* d_in, const int* in_sizes, int n_in,
                              void* d_out, int out_size, void* d_ws, size_t ws_size,
                              hipStream_t stream) {
    const float* item = nullptr;
    const int*   msk  = nullptr;
    const float* w    = nullptr;
    for (int i = 0; i < n_in; ++i) {
        if (in_sizes[i] == BDIM * SDIM * HDIM)             item = (const float*)d_in[i];
        else if (in_sizes[i] == BDIM * SDIM)               msk  = (const int*)d_in[i];
        else if (in_sizes[i] == SDIM * IDIM * HDIM * HDIM) w    = (const float*)d_in[i];
    }
    if (!item) item = (const float*)d_in[0];
    if (!msk)  msk  = (const int*)d_in[1];
    if (!w)    w    = (const float*)d_in[2];

    // ws layout: [w images 58.98 MB][hat chunk 209.7 MB]
    const size_t imgBytes = (size_t)SDIM * IDIM * IMG_US * sizeof(ushort);
    ushort* wimg = (ushort*)d_ws;
    float*  hat  = (float*)((char*)d_ws + imgBytes);
    float*  out  = (float*)d_out;

    wstage<<<SDIM * IDIM, 256, 0, stream>>>(w, wimg);

    const size_t perB = (size_t)IDIM * SDIM * HDIM * sizeof(float);
    size_t hatCap = (ws_size - imgBytes) / perB;
    int chunk = 512;
    if (hatCap < (size_t)chunk) chunk = (int)((hatCap / 128) * 128);
    if (chunk < 128) chunk = 128;
    for (int bb = 0; bb < BDIM; bb += chunk) {
        int cb = (BDIM - bb < chunk) ? (BDIM - bb) : chunk;
        int nbt = cb / 128;
        hat_gemm<<<nbt * SDIM, 256, 0, stream>>>(item, wimg, hat, bb);
        routing4<<<cb * IDIM, 512, 0, stream>>>(hat, msk, out, bb);
    }
}